// Round 4
// baseline (64.290 us; speedup 1.0000x reference)
//
#include <hip/hip_runtime.h>

// HardNegativeContrastiveLoss, B=8192, D=128, T=0.1, margin=0.5.
//
// Analytic collapse: the reference masks only the (i,B+i)/(B+i,i) pairs in
// neg_sim — NOT the diagonal. After row-normalization the diagonal entry is
// ||z_norm||^2 == 1, the maximum possible cosine similarity, so
// hardest_neg[row] is always the diagonal self-sim / T. The 16384^2 matmul
// collapses to three per-row dot products:
//   loss = mean over 2B rows of relu(self_sim/T + margin - pos_sim)
//
// R3 profile: dur_us dominated by harness reset (41 us d_ws fill + restores);
// controllable share ~12 us across two dispatches. This round: single fused
// dispatch. Blocks publish partials + a 64-bit magic flag (release, agent
// scope — G16 cross-XCD safety); the last block acquire-spins on all flags
// and finishes the reduction. No counter init needed (d_ws poison is 0xAA,
// not zero — flag magic can't collide with poison; stale-flag failure mode
// is benign since inputs are restored identically every replay).

constexpr int   kB      = 8192;
constexpr int   kD      = 128;
constexpr float kInvT   = 10.0f;     // 1 / 0.1
constexpr float kMargin = 0.5f;
constexpr int   kBlocks = 512;
constexpr unsigned long long kMagic = 0x13579BDF2468ACE0ull;

__global__ __launch_bounds__(256) void hncl_fused(const float* __restrict__ z1,
                                                  const float* __restrict__ z2,
                                                  float* __restrict__ ws,
                                                  float* __restrict__ out) {
    float* part = ws;                                                 // [512] partials
    unsigned long long* flags =
        reinterpret_cast<unsigned long long*>(ws + 1024);             // +4 KB: [512] flags

    const int lane        = threadIdx.x & 63;
    const int sub         = lane & 31;    // lane within 32-lane half
    const int half        = lane >> 5;    // which row of the wave's pair
    const int wave_in_blk = threadIdx.x >> 6;               // 0..3
    const int gwave       = blockIdx.x * 4 + wave_in_blk;   // 0..2047

    float local = 0.0f;

    // Each wave covers 2 rows/iter (32 lanes x float4 = 1 row, 16 B/lane).
    #pragma unroll
    for (int iter = 0; iter < 2; ++iter) {
        const int row = gwave * 2 + half + iter * (kB / 2);
        const float4 a = reinterpret_cast<const float4*>(z1 + (size_t)row * kD)[sub];
        const float4 b = reinterpret_cast<const float4*>(z2 + (size_t)row * kD)[sub];

        float d11 = a.x * a.x + a.y * a.y + a.z * a.z + a.w * a.w;
        float d22 = b.x * b.x + b.y * b.y + b.z * b.z + b.w * b.w;
        float d12 = a.x * b.x + a.y * b.y + a.z * b.z + a.w * b.w;

        #pragma unroll
        for (int off = 16; off > 0; off >>= 1) {
            d11 += __shfl_down(d11, off, 32);
            d22 += __shfl_down(d22, off, 32);
            d12 += __shfl_down(d12, off, 32);
        }

        if (sub == 0) {
            const float n1 = fmaxf(sqrtf(d11), 1e-12f);
            const float n2 = fmaxf(sqrtf(d22), 1e-12f);
            const float pos = d12 / (n1 * n2);
            const float s1  = d11 / (n1 * n1);   // == 1 up to rounding
            const float s2  = d22 / (n2 * n2);
            local += fmaxf(s1 * kInvT + kMargin - pos, 0.0f)
                   + fmaxf(s2 * kInvT + kMargin - pos, 0.0f);
        }
    }

    __shared__ float wsum[8];
    if (sub == 0) wsum[wave_in_blk * 2 + half] = local;
    __syncthreads();
    if (threadIdx.x == 0) {
        float s = 0.0f;
        #pragma unroll
        for (int i = 0; i < 8; ++i) s += wsum[i];
        // publish: data (relaxed) then flag (release), both agent scope
        __hip_atomic_store(&part[blockIdx.x], s,
                           __ATOMIC_RELAXED, __HIP_MEMORY_SCOPE_AGENT);
        __hip_atomic_store(&flags[blockIdx.x], kMagic,
                           __ATOMIC_RELEASE, __HIP_MEMORY_SCOPE_AGENT);
    }

    // Last block consumes all 512 partials. Co-residency guaranteed:
    // 512 blocks x 4 waves = 2048 waves << 8192-wave device capacity.
    if (blockIdx.x == kBlocks - 1) {
        const int t = threadIdx.x;   // 0..255 -> partials 2t, 2t+1
        while (__hip_atomic_load(&flags[2 * t], __ATOMIC_ACQUIRE,
                                 __HIP_MEMORY_SCOPE_AGENT) != kMagic)
            __builtin_amdgcn_s_sleep(1);
        while (__hip_atomic_load(&flags[2 * t + 1], __ATOMIC_ACQUIRE,
                                 __HIP_MEMORY_SCOPE_AGENT) != kMagic)
            __builtin_amdgcn_s_sleep(1);

        float v = __hip_atomic_load(&part[2 * t], __ATOMIC_RELAXED,
                                    __HIP_MEMORY_SCOPE_AGENT)
                + __hip_atomic_load(&part[2 * t + 1], __ATOMIC_RELAXED,
                                    __HIP_MEMORY_SCOPE_AGENT);
        #pragma unroll
        for (int off = 32; off > 0; off >>= 1) v += __shfl_down(v, off, 64);

        __shared__ float fsum[4];
        if (lane == 0) fsum[wave_in_blk] = v;
        __syncthreads();
        if (threadIdx.x == 0)
            out[0] = (fsum[0] + fsum[1] + fsum[2] + fsum[3])
                     * (1.0f / (2.0f * (float)kB));
    }
}

extern "C" void kernel_launch(void* const* d_in, const int* in_sizes, int n_in,
                              void* d_out, int out_size, void* d_ws, size_t ws_size,
                              hipStream_t stream) {
    const float* z1 = reinterpret_cast<const float*>(d_in[0]);
    const float* z2 = reinterpret_cast<const float*>(d_in[1]);
    float* ws  = reinterpret_cast<float*>(d_ws);
    float* out = reinterpret_cast<float*>(d_out);

    hncl_fused<<<kBlocks, 256, 0, stream>>>(z1, z2, ws, out);
}

// Round 5
// 61.135 us; speedup vs baseline: 1.0516x; 1.0516x over previous
//
#include <hip/hip_runtime.h>

// HardNegativeContrastiveLoss, B=8192, D=128, T=0.1, margin=0.5.
//
// Analytic collapse: the reference masks only the (i,B+i)/(B+i,i) pairs in
// neg_sim — NOT the diagonal. After row-normalization the diagonal entry is
// ||z_norm||^2 == 1, the maximum possible cosine similarity, so
// hardest_neg[row] is always the diagonal self-sim / T. The 16384^2 matmul
// collapses to three per-row dot products:
//   loss = mean over 2B rows of relu(self_sim/T + margin - pos_sim)
//
// R4 post-mortem: single-dispatch flag fusion REGRESSED (64.3 vs 60.6) —
// agent-scope release/acquire emits L2 writeback/invalidate traffic x512
// blocks plus per-poll invalidates in the consumer spin. Reverted to the
// two-dispatch plain-store structure (R3, prediction-matched 60.6 us).
// dur_us is dominated by the harness's 256 MB d_ws re-poison (41 us fill,
// 100% of profile top-5) + input restores (~46-48 us floor). This round's
// only change: k2 shrunk to ONE wave (64 lanes x 2 float4 = 512 partials,
// pure shuffle reduce, no LDS/barrier) to trim the serial k1->k2 tail.

constexpr int   kB      = 8192;
constexpr int   kD      = 128;
constexpr float kInvT   = 10.0f;     // 1 / 0.1
constexpr float kMargin = 0.5f;
constexpr int   kBlocks = 512;       // k1 grid; d_ws holds kBlocks floats

__global__ __launch_bounds__(256) void hncl_partial(const float* __restrict__ z1,
                                                    const float* __restrict__ z2,
                                                    float* __restrict__ ws) {
    const int lane        = threadIdx.x & 63;
    const int sub         = lane & 31;    // lane within 32-lane half
    const int half        = lane >> 5;    // which row of the wave's pair
    const int wave_in_blk = threadIdx.x >> 6;               // 0..3
    const int gwave       = blockIdx.x * 4 + wave_in_blk;   // 0..2047

    float local = 0.0f;

    // Each wave covers 2 rows/iter (32 lanes x float4 = 1 row, 16 B/lane);
    // adjacent rows contiguous -> the wave reads 1 KB contiguous per array.
    #pragma unroll
    for (int iter = 0; iter < 2; ++iter) {
        const int row = gwave * 2 + half + iter * (kB / 2);
        const float4 a = reinterpret_cast<const float4*>(z1 + (size_t)row * kD)[sub];
        const float4 b = reinterpret_cast<const float4*>(z2 + (size_t)row * kD)[sub];

        float d11 = a.x * a.x + a.y * a.y + a.z * a.z + a.w * a.w;
        float d22 = b.x * b.x + b.y * b.y + b.z * b.z + b.w * b.w;
        float d12 = a.x * b.x + a.y * b.y + a.z * b.z + a.w * b.w;

        // reduce within the 32-lane half
        #pragma unroll
        for (int off = 16; off > 0; off >>= 1) {
            d11 += __shfl_down(d11, off, 32);
            d22 += __shfl_down(d22, off, 32);
            d12 += __shfl_down(d12, off, 32);
        }

        if (sub == 0) {
            const float n1 = fmaxf(sqrtf(d11), 1e-12f);
            const float n2 = fmaxf(sqrtf(d22), 1e-12f);
            const float pos = d12 / (n1 * n2);
            const float s1  = d11 / (n1 * n1);   // == 1 up to rounding
            const float s2  = d22 / (n2 * n2);
            local += fmaxf(s1 * kInvT + kMargin - pos, 0.0f)
                   + fmaxf(s2 * kInvT + kMargin - pos, 0.0f);
        }
    }

    __shared__ float wsum[8];
    if (sub == 0) wsum[wave_in_blk * 2 + half] = local;
    __syncthreads();
    if (threadIdx.x == 0) {
        float s = 0.0f;
        #pragma unroll
        for (int i = 0; i < 8; ++i) s += wsum[i];
        ws[blockIdx.x] = s;   // plain store — overwrites poison, no atomics
    }
}

// Single wave: 64 lanes x 2 float4 = 512 partials. No LDS, no barrier.
__global__ __launch_bounds__(64) void hncl_final(const float* __restrict__ ws,
                                                 float* __restrict__ out) {
    const float4* w4 = reinterpret_cast<const float4*>(ws);
    const float4 p0 = w4[threadIdx.x * 2];
    const float4 p1 = w4[threadIdx.x * 2 + 1];
    float v = (p0.x + p0.y + p0.z + p0.w) + (p1.x + p1.y + p1.z + p1.w);
    #pragma unroll
    for (int off = 32; off > 0; off >>= 1) v += __shfl_down(v, off, 64);
    if (threadIdx.x == 0)
        out[0] = v * (1.0f / (2.0f * (float)kB));   // plain store, no memset
}

extern "C" void kernel_launch(void* const* d_in, const int* in_sizes, int n_in,
                              void* d_out, int out_size, void* d_ws, size_t ws_size,
                              hipStream_t stream) {
    const float* z1 = reinterpret_cast<const float*>(d_in[0]);
    const float* z2 = reinterpret_cast<const float*>(d_in[1]);
    float* ws  = reinterpret_cast<float*>(d_ws);
    float* out = reinterpret_cast<float*>(d_out);

    hncl_partial<<<kBlocks, 256, 0, stream>>>(z1, z2, ws);
    hncl_final<<<1, 64, 0, stream>>>(ws, out);
}